// Round 5
// baseline (3769.961 us; speedup 1.0000x reference)
//
#include <hip/hip_runtime.h>
#include <stdint.h>

#define NN   50000
#define NE   1600000
#define DIN  128
#define DMID 256
#define DOUT 128
#define NMID 8

typedef unsigned short u16;
typedef unsigned int   u32;
typedef __attribute__((ext_vector_type(8))) short short8;
typedef __attribute__((ext_vector_type(4))) float f32x4;
typedef __attribute__((ext_vector_type(2))) float f32x2;

__device__ __forceinline__ float bf2f(u32 u) {
    union { u32 i; float f; } c; c.i = u << 16; return c.f;
}
__device__ __forceinline__ u16 f2bf(float f) {
    union { float f; u32 i; } c; c.f = f;
    u32 u = c.i;
    return (u16)((u + 0x7fffu + ((u >> 16) & 1u)) >> 16);
}
__device__ __forceinline__ void split2(float v, u16& hi, u16& lo) {
    hi = f2bf(v);
    float r = v - bf2f(hi);
    lo = f2bf(r);
}

// ---------------- preprocessing kernels ----------------

__global__ void hist_kernel(const int* __restrict__ ei, int* __restrict__ counts) {
    int i = blockIdx.x * blockDim.x + threadIdx.x;
    int stride = gridDim.x * blockDim.x;
    for (; i < NE; i += stride) atomicAdd(&counts[ei[NE + i]], 1);
}

__global__ void dinv_kernel(const int* __restrict__ counts, float* __restrict__ dinv) {
    int i = blockIdx.x * blockDim.x + threadIdx.x;
    if (i < NN) dinv[i] = rsqrtf((float)counts[i] + 1.0f);
}

__global__ __launch_bounds__(1024) void scan_kernel(const int* __restrict__ counts,
                                                    int* __restrict__ rowp,
                                                    int* __restrict__ cursor) {
    __shared__ int sh[1024];
    const int t = threadIdx.x;
    constexpr int ITEMS = (NN + 1023) / 1024;  // 49
    const int start = t * ITEMS;
    int sum = 0;
    for (int j = 0; j < ITEMS; ++j) {
        int idx = start + j;
        if (idx < NN) sum += counts[idx];
    }
    sh[t] = sum;
    __syncthreads();
    for (int offs = 1; offs < 1024; offs <<= 1) {
        int v = (t >= offs) ? sh[t - offs] : 0;
        __syncthreads();
        sh[t] += v;
        __syncthreads();
    }
    int base = (t == 0) ? 0 : sh[t - 1];
    for (int j = 0; j < ITEMS; ++j) {
        int idx = start + j;
        if (idx < NN) {
            rowp[idx] = base;
            cursor[idx] = base;
            base += counts[idx];
        }
    }
    if (t == 0) rowp[NN] = NE;
}

__global__ void fill_kernel(const int* __restrict__ ei, int* __restrict__ cursor,
                            int* __restrict__ srcs) {
    int i = blockIdx.x * blockDim.x + threadIdx.x;
    int stride = gridDim.x * blockDim.x;
    for (; i < NE; i += stride) {
        int d = ei[NE + i];
        int pos = atomicAdd(&cursor[d], 1);
        srcs[pos] = ei[i];
    }
}

// W [K x Dc] fp32 row-major  ->  Wt_hi/Wt_lo [Dc x K] bf16 split
__global__ void wsplit_kernel(const float* __restrict__ W, u16* __restrict__ Whi,
                              u16* __restrict__ Wlo, int K, int Dc) {
    int idx = blockIdx.x * blockDim.x + threadIdx.x;
    if (idx < K * Dc) {
        int k = idx / Dc, d = idx - k * Dc;
        u16 hi, lo;
        split2(W[idx], hi, lo);
        Whi[d * K + k] = hi;
        Wlo[d * K + k] = lo;
    }
}

// x [NN][128] fp32 -> chunk-major [4][NN][32] bf16 hi/lo
__global__ void xsplit_kernel(const float* __restrict__ x, u16* __restrict__ xhi,
                              u16* __restrict__ xlo) {
    int i = blockIdx.x * blockDim.x + threadIdx.x;
    int stride = gridDim.x * blockDim.x;
    for (; i < NN * DIN; i += stride) {
        int node = i >> 7, col = i & 127;
        int c = col >> 5, wi = col & 31;
        size_t o = ((size_t)c * NN + node) * 32 + wi;
        u16 hi, lo;
        split2(x[i], hi, lo);
        xhi[o] = hi;
        xlo[o] = lo;
    }
}

// ---------------- GEMM: g = (x @ W) * dinv[row], bf16 chunk-major out ---------
// x chunk-major [K/32][NN][32] bf16 hi+lo; W transposed [Dc][K] bf16 hi+lo.
// acc = xh*Wh + xl*Wh + xh*Wl. block = 256 = 4 waves; wave: 16 rows x Dc cols.
// C/D: col=lane&15, row=(lane>>4)*4+reg

template <int K, int Dc>
__global__ __launch_bounds__(256) void gemm_kernel(const u16* __restrict__ xhi,
                                                   const u16* __restrict__ xlo,
                                                   const u16* __restrict__ whi,
                                                   const u16* __restrict__ wlo,
                                                   const float* __restrict__ dinv,
                                                   u16* __restrict__ g) {
    constexpr int NT = Dc / 16;
    constexpr int KS = K / 32;
    const int wid = threadIdx.x >> 6;
    const int lane = threadIdx.x & 63;
    const int rowBase = blockIdx.x * 64 + wid * 16;
    if (rowBase >= NN) return;
    const int m = lane & 15, quad = lane >> 4;
    int rowA = rowBase + m;
    if (rowA > NN - 1) rowA = NN - 1;

    f32x4 acc[NT];
#pragma unroll
    for (int t = 0; t < NT; ++t) acc[t] = (f32x4){0.f, 0.f, 0.f, 0.f};

    const u16* ph = xhi + (size_t)rowA * 32 + quad * 8;
    const u16* pl = xlo + (size_t)rowA * 32 + quad * 8;
#pragma unroll
    for (int ks = 0; ks < KS; ++ks) {
        short8 ah = *(const short8*)(ph + (size_t)ks * NN * 32);
        short8 al = *(const short8*)(pl + (size_t)ks * NN * 32);
#pragma unroll
        for (int t = 0; t < NT; ++t) {
            size_t woff = (size_t)(t * 16 + m) * K + ks * 32 + quad * 8;
            short8 wh = *(const short8*)(whi + woff);
            short8 wl = *(const short8*)(wlo + woff);
            acc[t] = __builtin_amdgcn_mfma_f32_16x16x32_bf16(ah, wh, acc[t], 0, 0, 0);
            acc[t] = __builtin_amdgcn_mfma_f32_16x16x32_bf16(al, wh, acc[t], 0, 0, 0);
            acc[t] = __builtin_amdgcn_mfma_f32_16x16x32_bf16(ah, wl, acc[t], 0, 0, 0);
        }
    }

    const int r0 = rowBase + quad * 4;
    float dv[4];
#pragma unroll
    for (int r = 0; r < 4; ++r) {
        int rr = r0 + r;
        dv[r] = (rr < NN) ? dinv[rr] : 0.f;
    }
#pragma unroll
    for (int t = 0; t < NT; ++t) {
        const int col = t * 16 + m;
        const int c = col >> 5, wi = col & 31;
#pragma unroll
        for (int r = 0; r < 4; ++r) {
            int rr = r0 + r;
            if (rr < NN) g[((size_t)c * NN + rr) * 32 + wi] = f2bf(acc[t][r] * dv[r]);
        }
    }
}

// ---------------- chunked aggregation ----------------
// grid = (NN/4, C); wave per node; lane = (slot=lane>>4, colpair=lane&15).
// Each neighbor's 32-col bf16 chunk row = one 64B line; 4 neighbors per wave inst.
// Writes bf16 sums (self + neighbors, unscaled) chunk-major into aggbuf.

__global__ __launch_bounds__(256) void agg_chunk_kernel(const u16* __restrict__ g,
                                                        const int* __restrict__ rowp,
                                                        const int* __restrict__ srcs,
                                                        u16* __restrict__ aggbuf) {
    const int wid = threadIdx.x >> 6, lane = threadIdx.x & 63;
    const int node = blockIdx.x * 4 + wid;
    const u16* gc = g + (size_t)blockIdx.y * (NN * 32);
    u16* ac = aggbuf + (size_t)blockIdx.y * (NN * 32);
    const int cp = lane & 15;    // cols 2cp, 2cp+1
    const int slot = lane >> 4;  // 0..3

    float a0 = 0.f, a1 = 0.f;
    const int end = rowp[node + 1];
    int e = rowp[node] + slot;
    for (; e + 4 < end; e += 8) {
        int s0 = srcs[e], s1 = srcs[e + 4];
        u32 v0 = *(const u32*)(gc + (size_t)s0 * 32 + cp * 2);
        u32 v1 = *(const u32*)(gc + (size_t)s1 * 32 + cp * 2);
        a0 += bf2f(v0 & 0xffffu) + bf2f(v1 & 0xffffu);
        a1 += bf2f(v0 >> 16) + bf2f(v1 >> 16);
    }
    if (e < end) {
        int s = srcs[e];
        u32 v = *(const u32*)(gc + (size_t)s * 32 + cp * 2);
        a0 += bf2f(v & 0xffffu);
        a1 += bf2f(v >> 16);
    }
    if (slot == 0) {  // self term
        u32 v = *(const u32*)(gc + (size_t)node * 32 + cp * 2);
        a0 += bf2f(v & 0xffffu);
        a1 += bf2f(v >> 16);
    }
    a0 += __shfl_xor(a0, 16, 64);
    a1 += __shfl_xor(a1, 16, 64);
    a0 += __shfl_xor(a0, 32, 64);
    a1 += __shfl_xor(a1, 32, 64);
    if (slot == 0)
        *(u32*)(ac + (size_t)node * 32 + cp * 2) = (u32)f2bf(a0) | ((u32)f2bf(a1) << 16);
}

// ---------------- LN + SiLU epilogue (mid layers) ----------------
// reads bf16 sums chunk-major (agghi), applies dinv*sum + bias, LN, SiLU,
// writes bf16 hi in-place over agghi and lo into xlo (both chunk-major).

__global__ __launch_bounds__(256) void ln_epilogue_kernel(u16* __restrict__ agghi,
                                                          u16* __restrict__ xlo,
                                                          const float* __restrict__ dinv,
                                                          const float* __restrict__ bias,
                                                          const float* __restrict__ gamma,
                                                          const float* __restrict__ beta) {
    const int wid = threadIdx.x >> 6, lane = threadIdx.x & 63;
    const int node = blockIdx.x * 4 + wid;
    const int coff = lane * 4;
    const int c = coff >> 5, wi = coff & 31;
    const size_t off = ((size_t)c * NN + node) * 32 + wi;

    uint2 raw = *(const uint2*)(agghi + off);
    const float dv = dinv[node];
    float v[4];
    v[0] = bf2f(raw.x & 0xffffu) * dv + bias[coff];
    v[1] = bf2f(raw.x >> 16) * dv + bias[coff + 1];
    v[2] = bf2f(raw.y & 0xffffu) * dv + bias[coff + 2];
    v[3] = bf2f(raw.y >> 16) * dv + bias[coff + 3];

    float s = (v[0] + v[1]) + (v[2] + v[3]);
    float s2 = (v[0] * v[0] + v[1] * v[1]) + (v[2] * v[2] + v[3] * v[3]);
    for (int o = 32; o > 0; o >>= 1) {
        s += __shfl_xor(s, o, 64);
        s2 += __shfl_xor(s2, o, 64);
    }
    const float mu = s * (1.f / DMID);
    const float var = s2 * (1.f / DMID) - mu * mu;
    const float rstd = rsqrtf(fmaxf(var, 0.f) + 1e-5f);

    u16 hh[4], ll[4];
#pragma unroll
    for (int j = 0; j < 4; ++j) {
        float y = (v[j] - mu) * rstd * gamma[coff + j] + beta[coff + j];
        y = y / (1.f + __expf(-y));
        split2(y, hh[j], ll[j]);
    }
    uint2 oh, ol;
    oh.x = (u32)hh[0] | ((u32)hh[1] << 16);
    oh.y = (u32)hh[2] | ((u32)hh[3] << 16);
    ol.x = (u32)ll[0] | ((u32)ll[1] << 16);
    ol.y = (u32)ll[2] | ((u32)ll[3] << 16);
    *(uint2*)(agghi + off) = oh;
    *(uint2*)(xlo + off) = ol;
}

// ---------------- final epilogue: dinv*sum + bias -> fp32 d_out ----------------

__global__ __launch_bounds__(256) void final_epilogue_kernel(const u16* __restrict__ aggbuf,
                                                             const float* __restrict__ dinv,
                                                             const float* __restrict__ bias,
                                                             float* __restrict__ out) {
    const int wid = threadIdx.x >> 6, lane = threadIdx.x & 63;
    const int node = blockIdx.x * 4 + wid;
    const int coff = lane * 2;
    const int c = coff >> 5, wi = coff & 31;
    u32 raw = *(const u32*)(aggbuf + ((size_t)c * NN + node) * 32 + wi);
    const float dv = dinv[node];
    f32x2 o;
    o[0] = bf2f(raw & 0xffffu) * dv + bias[coff];
    o[1] = bf2f(raw >> 16) * dv + bias[coff + 1];
    *(f32x2*)(out + (size_t)node * DOUT + coff) = o;
}

// ---------------- launcher ----------------

extern "C" void kernel_launch(void* const* d_in, const int* in_sizes, int n_in,
                              void* d_out, int out_size, void* d_ws, size_t ws_size,
                              hipStream_t stream) {
    (void)in_sizes; (void)n_in; (void)out_size; (void)ws_size;
    const float* x_in  = (const float*)d_in[0];
    const int*   ei    = (const int*)d_in[1];
    const float* W_in  = (const float*)d_in[2];
    const float* b_in  = (const float*)d_in[3];
    const float* W_mid = (const float*)d_in[4];
    const float* b_mid = (const float*)d_in[5];
    const float* W_out = (const float*)d_in[6];
    const float* b_out = (const float*)d_in[7];
    const float* gamma = (const float*)d_in[8];
    const float* beta  = (const float*)d_in[9];

    char* ws = (char*)d_ws;
    size_t off = 0;
    auto alloc = [&](size_t bytes) -> char* {
        char* p = ws + off;
        off += (bytes + 255) & ~(size_t)255;
        return p;
    };
    float* dinv   = (float*)alloc((size_t)NN * 4);
    int* counts   = (int*)alloc((size_t)NN * 4);
    int* rowp     = (int*)alloc((size_t)(NN + 1) * 4);
    int* cursor   = (int*)alloc((size_t)NN * 4);
    int* srcs     = (int*)alloc((size_t)NE * 4);
    u16* whi_in   = (u16*)alloc((size_t)DIN * DMID * 2);
    u16* wlo_in   = (u16*)alloc((size_t)DIN * DMID * 2);
    u16* whi_mid  = (u16*)alloc((size_t)NMID * DMID * DMID * 2);
    u16* wlo_mid  = (u16*)alloc((size_t)NMID * DMID * DMID * 2);
    u16* whi_out  = (u16*)alloc((size_t)DMID * DOUT * 2);
    u16* wlo_out  = (u16*)alloc((size_t)DMID * DOUT * 2);
    u16* xhi      = (u16*)alloc((size_t)NN * DMID * 2);  // doubles as aggbuf
    u16* xlo      = (u16*)alloc((size_t)NN * DMID * 2);
    u16* g        = (u16*)alloc((size_t)NN * DMID * 2);

    hipMemsetAsync(counts, 0, (size_t)NN * 4, stream);
    hist_kernel<<<1024, 256, 0, stream>>>(ei, counts);
    dinv_kernel<<<(NN + 255) / 256, 256, 0, stream>>>(counts, dinv);
    scan_kernel<<<1, 1024, 0, stream>>>(counts, rowp, cursor);
    fill_kernel<<<1024, 256, 0, stream>>>(ei, cursor, srcs);

    wsplit_kernel<<<(DIN * DMID + 255) / 256, 256, 0, stream>>>(W_in, whi_in, wlo_in, DIN, DMID);
    for (int i = 0; i < NMID; ++i)
        wsplit_kernel<<<(DMID * DMID + 255) / 256, 256, 0, stream>>>(
            W_mid + (size_t)i * DMID * DMID, whi_mid + (size_t)i * DMID * DMID,
            wlo_mid + (size_t)i * DMID * DMID, DMID, DMID);
    wsplit_kernel<<<(DMID * DOUT + 255) / 256, 256, 0, stream>>>(W_out, whi_out, wlo_out, DMID, DOUT);
    xsplit_kernel<<<1024, 256, 0, stream>>>(x_in, xhi, xlo);

    const int GB = (NN + 63) / 64;   // 782
    const int NB = NN / 4;           // 12500 (4 waves/block, wave per node)
    const dim3 AGRID8(NB, 8);        // node-blocks x chunks
    const dim3 AGRID4(NB, 4);

    // layer 0: 128 -> 256
    gemm_kernel<DIN, DMID><<<GB, 256, 0, stream>>>(xhi, xlo, whi_in, wlo_in, dinv, g);
    agg_chunk_kernel<<<AGRID8, 256, 0, stream>>>(g, rowp, srcs, xhi);
    ln_epilogue_kernel<<<NB, 256, 0, stream>>>(xhi, xlo, dinv, b_in, gamma, beta);
    // 8 mid layers: 256 -> 256
    for (int i = 0; i < NMID; ++i) {
        gemm_kernel<DMID, DMID><<<GB, 256, 0, stream>>>(xhi, xlo,
                                                        whi_mid + (size_t)i * DMID * DMID,
                                                        wlo_mid + (size_t)i * DMID * DMID,
                                                        dinv, g);
        agg_chunk_kernel<<<AGRID8, 256, 0, stream>>>(g, rowp, srcs, xhi);
        ln_epilogue_kernel<<<NB, 256, 0, stream>>>(xhi, xlo, dinv, b_mid + (size_t)i * DMID,
                                                   gamma + (size_t)(i + 1) * DMID,
                                                   beta + (size_t)(i + 1) * DMID);
    }
    // final layer: 256 -> 128, no LN/SiLU
    gemm_kernel<DMID, DOUT><<<GB, 256, 0, stream>>>(xhi, xlo, whi_out, wlo_out, dinv, g);
    agg_chunk_kernel<<<AGRID4, 256, 0, stream>>>(g, rowp, srcs, xhi);
    final_epilogue_kernel<<<NB, 256, 0, stream>>>(xhi, dinv, b_out, (float*)d_out);
}

// Round 6
// 2943.380 us; speedup vs baseline: 1.2808x; 1.2808x over previous
//
#include <hip/hip_runtime.h>
#include <stdint.h>

#define NN   50000
#define NE   1600000
#define DIN  128
#define DMID 256
#define DOUT 128
#define NMID 8

#define AS1 __attribute__((address_space(1)))
#define AS3 __attribute__((address_space(3)))

typedef unsigned short u16;
typedef unsigned int   u32;
typedef __attribute__((ext_vector_type(8))) short short8;
typedef __attribute__((ext_vector_type(4))) float f32x4;
typedef __attribute__((ext_vector_type(2))) float f32x2;

__device__ __forceinline__ float bf2f(u32 u) {
    union { u32 i; float f; } c; c.i = u << 16; return c.f;
}
__device__ __forceinline__ u16 f2bf(float f) {
    union { float f; u32 i; } c; c.f = f;
    u32 u = c.i;
    return (u16)((u + 0x7fffu + ((u >> 16) & 1u)) >> 16);
}
__device__ __forceinline__ void split2(float v, u16& hi, u16& lo) {
    hi = f2bf(v);
    float r = v - bf2f(hi);
    lo = f2bf(r);
}

// ---------------- preprocessing kernels ----------------

__global__ void hist_kernel(const int* __restrict__ ei, int* __restrict__ counts) {
    int i = blockIdx.x * blockDim.x + threadIdx.x;
    int stride = gridDim.x * blockDim.x;
    for (; i < NE; i += stride) atomicAdd(&counts[ei[NE + i]], 1);
}

__global__ void dinv_kernel(const int* __restrict__ counts, float* __restrict__ dinv) {
    int i = blockIdx.x * blockDim.x + threadIdx.x;
    if (i < NN) dinv[i] = rsqrtf((float)counts[i] + 1.0f);
}

__global__ __launch_bounds__(1024) void scan_kernel(const int* __restrict__ counts,
                                                    int* __restrict__ rowp,
                                                    int* __restrict__ cursor) {
    __shared__ int sh[1024];
    const int t = threadIdx.x;
    constexpr int ITEMS = (NN + 1023) / 1024;  // 49
    const int start = t * ITEMS;
    int sum = 0;
    for (int j = 0; j < ITEMS; ++j) {
        int idx = start + j;
        if (idx < NN) sum += counts[idx];
    }
    sh[t] = sum;
    __syncthreads();
    for (int offs = 1; offs < 1024; offs <<= 1) {
        int v = (t >= offs) ? sh[t - offs] : 0;
        __syncthreads();
        sh[t] += v;
        __syncthreads();
    }
    int base = (t == 0) ? 0 : sh[t - 1];
    for (int j = 0; j < ITEMS; ++j) {
        int idx = start + j;
        if (idx < NN) {
            rowp[idx] = base;
            cursor[idx] = base;
            base += counts[idx];
        }
    }
    if (t == 0) rowp[NN] = NE;
}

__global__ void fill_kernel(const int* __restrict__ ei, int* __restrict__ cursor,
                            int* __restrict__ srcs) {
    int i = blockIdx.x * blockDim.x + threadIdx.x;
    int stride = gridDim.x * blockDim.x;
    for (; i < NE; i += stride) {
        int d = ei[NE + i];
        int pos = atomicAdd(&cursor[d], 1);
        srcs[pos] = ei[i];
    }
}

// W [K x Dc] fp32 row-major -> slice-major bf16 split: Whi[(k/32)*Dc + d][32]
__global__ void wsplit_kernel(const float* __restrict__ W, u16* __restrict__ Whi,
                              u16* __restrict__ Wlo, int K, int Dc) {
    int idx = blockIdx.x * blockDim.x + threadIdx.x;
    if (idx < K * Dc) {
        int k = idx / Dc, d = idx - k * Dc;
        u16 hi, lo;
        split2(W[idx], hi, lo);
        size_t o = ((size_t)(k >> 5) * Dc + d) * 32 + (k & 31);
        Whi[o] = hi;
        Wlo[o] = lo;
    }
}

// x [NN][128] fp32 -> chunk-major [4][NN][32] bf16 hi/lo
__global__ void xsplit_kernel(const float* __restrict__ x, u16* __restrict__ xhi,
                              u16* __restrict__ xlo) {
    int i = blockIdx.x * blockDim.x + threadIdx.x;
    int stride = gridDim.x * blockDim.x;
    for (; i < NN * DIN; i += stride) {
        int node = i >> 7, col = i & 127;
        int c = col >> 5, wi = col & 31;
        size_t o = ((size_t)c * NN + node) * 32 + wi;
        u16 hi, lo;
        split2(x[i], hi, lo);
        xhi[o] = hi;
        xlo[o] = lo;
    }
}

// ---------------- GEMM: g = (x @ W) * dinv[row], bf16 chunk-major out ---------
// x chunk-major [K/32][NN][32] bf16 hi+lo; W slice-major [K/32][Dc][32] bf16 hi+lo.
// Per K-slice: stage B-slice (Dc x 32) hi+lo into LDS with global_load_lds(16B),
// then each wave does ds_read_b128 fragments + 3-pass split-bf16 MFMA.
// block = 256 = 4 waves; wave: 16 rows x Dc cols. C/D: col=lane&15, row=quad*4+reg.

template <int K, int Dc>
__global__ __launch_bounds__(256) void gemm_kernel(const u16* __restrict__ xhi,
                                                   const u16* __restrict__ xlo,
                                                   const u16* __restrict__ whi,
                                                   const u16* __restrict__ wlo,
                                                   const float* __restrict__ dinv,
                                                   u16* __restrict__ g) {
    constexpr int NT = Dc / 16;
    constexpr int KS = K / 32;
    __shared__ u16 bh[Dc * 32];
    __shared__ u16 bl[Dc * 32];
    const int tid = threadIdx.x;
    const int wid = tid >> 6;
    const int lane = tid & 63;
    const int m = lane & 15, quad = lane >> 4;
    const int rowBase = blockIdx.x * 64 + wid * 16;
    int rowA = rowBase + m;
    if (rowA > NN - 1) rowA = NN - 1;  // clamp; no early return (barriers!)

    f32x4 acc[NT];
#pragma unroll
    for (int t = 0; t < NT; ++t) acc[t] = (f32x4){0.f, 0.f, 0.f, 0.f};

    for (int ks = 0; ks < KS; ++ks) {
        const u16* sh_src = whi + (size_t)ks * Dc * 32;
        const u16* sl_src = wlo + (size_t)ks * Dc * 32;
        __syncthreads();  // protect LDS from previous iteration's readers
#pragma unroll
        for (int i = 0; i < Dc * 4; i += 256) {
            int j = i + tid;
            __builtin_amdgcn_global_load_lds((const AS1 void*)(sh_src + j * 8),
                                             (AS3 void*)((AS3 u16*)bh + j * 8), 16, 0, 0);
            __builtin_amdgcn_global_load_lds((const AS1 void*)(sl_src + j * 8),
                                             (AS3 void*)((AS3 u16*)bl + j * 8), 16, 0, 0);
        }
        short8 ah = *(const short8*)(xhi + ((size_t)ks * NN + rowA) * 32 + quad * 8);
        short8 al = *(const short8*)(xlo + ((size_t)ks * NN + rowA) * 32 + quad * 8);
        __syncthreads();  // staging complete
#pragma unroll
        for (int t = 0; t < NT; ++t) {
            const int bo = (t * 16 + m) * 32 + quad * 8;
            short8 wh = *(const short8*)(bh + bo);
            short8 wl = *(const short8*)(bl + bo);
            acc[t] = __builtin_amdgcn_mfma_f32_16x16x32_bf16(ah, wh, acc[t], 0, 0, 0);
            acc[t] = __builtin_amdgcn_mfma_f32_16x16x32_bf16(al, wh, acc[t], 0, 0, 0);
            acc[t] = __builtin_amdgcn_mfma_f32_16x16x32_bf16(ah, wl, acc[t], 0, 0, 0);
        }
    }

    const int r0 = rowBase + quad * 4;
    float dv[4];
#pragma unroll
    for (int r = 0; r < 4; ++r) {
        int rr = r0 + r;
        dv[r] = (rr < NN) ? dinv[rr] : 0.f;
    }
#pragma unroll
    for (int t = 0; t < NT; ++t) {
        const int col = t * 16 + m;
        const int c = col >> 5, wi = col & 31;
#pragma unroll
        for (int r = 0; r < 4; ++r) {
            int rr = r0 + r;
            if (rr < NN) g[((size_t)c * NN + rr) * 32 + wi] = f2bf(acc[t][r] * dv[r]);
        }
    }
}

// ---------------- chunked aggregation v2 ----------------
// grid = (NN/4, C); 4 waves/block, wave per node.
// lane = (slot=lane>>3, lp=lane&7): 8 lanes per edge, dwordx2 (8B = 4 cols) each;
// one wave-load covers 8 edges' 64B chunk rows. Shuffle-reduce across slots.

__global__ __launch_bounds__(256) void agg_chunk_kernel(const u16* __restrict__ g,
                                                        const int* __restrict__ rowp,
                                                        const int* __restrict__ srcs,
                                                        u16* __restrict__ aggbuf) {
    const int wid = threadIdx.x >> 6, lane = threadIdx.x & 63;
    const int node = blockIdx.x * 4 + wid;
    const u16* gc = g + (size_t)blockIdx.y * (NN * 32);
    u16* ac = aggbuf + (size_t)blockIdx.y * (NN * 32);
    const int slot = lane >> 3;  // 0..7  (edge within group of 8)
    const int lp = lane & 7;     // 8B chunk within 64B row

    const int start = rowp[node], end = rowp[node + 1];
    float a0 = 0.f, a1 = 0.f, a2 = 0.f, a3 = 0.f;
    for (int e = start; e < end; e += 8) {
        int idx = e + slot;
        bool ok = idx < end;
        int s = srcs[ok ? idx : end - 1];  // end-1 >= 0 guaranteed when loop entered
        uint2 v = *(const uint2*)(gc + (size_t)s * 32 + lp * 4);
        u32 vx = ok ? v.x : 0u;
        u32 vy = ok ? v.y : 0u;
        a0 += bf2f(vx & 0xffffu); a1 += bf2f(vx >> 16);
        a2 += bf2f(vy & 0xffffu); a3 += bf2f(vy >> 16);
    }
    if (slot == 0) {  // self term
        uint2 v = *(const uint2*)(gc + (size_t)node * 32 + lp * 4);
        a0 += bf2f(v.x & 0xffffu); a1 += bf2f(v.x >> 16);
        a2 += bf2f(v.y & 0xffffu); a3 += bf2f(v.y >> 16);
    }
#pragma unroll
    for (int off = 8; off < 64; off <<= 1) {
        a0 += __shfl_xor(a0, off, 64);
        a1 += __shfl_xor(a1, off, 64);
        a2 += __shfl_xor(a2, off, 64);
        a3 += __shfl_xor(a3, off, 64);
    }
    if (slot == 0) {
        uint2 o;
        o.x = (u32)f2bf(a0) | ((u32)f2bf(a1) << 16);
        o.y = (u32)f2bf(a2) | ((u32)f2bf(a3) << 16);
        *(uint2*)(ac + (size_t)node * 32 + lp * 4) = o;
    }
}

// ---------------- LN + SiLU epilogue (mid layers) ----------------

__global__ __launch_bounds__(256) void ln_epilogue_kernel(u16* __restrict__ agghi,
                                                          u16* __restrict__ xlo,
                                                          const float* __restrict__ dinv,
                                                          const float* __restrict__ bias,
                                                          const float* __restrict__ gamma,
                                                          const float* __restrict__ beta) {
    const int wid = threadIdx.x >> 6, lane = threadIdx.x & 63;
    const int node = blockIdx.x * 4 + wid;
    const int coff = lane * 4;
    const int c = coff >> 5, wi = coff & 31;
    const size_t off = ((size_t)c * NN + node) * 32 + wi;

    uint2 raw = *(const uint2*)(agghi + off);
    const float dv = dinv[node];
    float v[4];
    v[0] = bf2f(raw.x & 0xffffu) * dv + bias[coff];
    v[1] = bf2f(raw.x >> 16) * dv + bias[coff + 1];
    v[2] = bf2f(raw.y & 0xffffu) * dv + bias[coff + 2];
    v[3] = bf2f(raw.y >> 16) * dv + bias[coff + 3];

    float s = (v[0] + v[1]) + (v[2] + v[3]);
    float s2 = (v[0] * v[0] + v[1] * v[1]) + (v[2] * v[2] + v[3] * v[3]);
    for (int o = 32; o > 0; o >>= 1) {
        s += __shfl_xor(s, o, 64);
        s2 += __shfl_xor(s2, o, 64);
    }
    const float mu = s * (1.f / DMID);
    const float var = s2 * (1.f / DMID) - mu * mu;
    const float rstd = rsqrtf(fmaxf(var, 0.f) + 1e-5f);

    u16 hh[4], ll[4];
#pragma unroll
    for (int j = 0; j < 4; ++j) {
        float y = (v[j] - mu) * rstd * gamma[coff + j] + beta[coff + j];
        y = y / (1.f + __expf(-y));
        split2(y, hh[j], ll[j]);
    }
    uint2 oh, ol;
    oh.x = (u32)hh[0] | ((u32)hh[1] << 16);
    oh.y = (u32)hh[2] | ((u32)hh[3] << 16);
    ol.x = (u32)ll[0] | ((u32)ll[1] << 16);
    ol.y = (u32)ll[2] | ((u32)ll[3] << 16);
    *(uint2*)(agghi + off) = oh;
    *(uint2*)(xlo + off) = ol;
}

// ---------------- final epilogue: dinv*sum + bias -> fp32 d_out ----------------

__global__ __launch_bounds__(256) void final_epilogue_kernel(const u16* __restrict__ aggbuf,
                                                             const float* __restrict__ dinv,
                                                             const float* __restrict__ bias,
                                                             float* __restrict__ out) {
    const int wid = threadIdx.x >> 6, lane = threadIdx.x & 63;
    const int node = blockIdx.x * 4 + wid;
    const int coff = lane * 2;
    const int c = coff >> 5, wi = coff & 31;
    u32 raw = *(const u32*)(aggbuf + ((size_t)c * NN + node) * 32 + wi);
    const float dv = dinv[node];
    f32x2 o;
    o[0] = bf2f(raw & 0xffffu) * dv + bias[coff];
    o[1] = bf2f(raw >> 16) * dv + bias[coff + 1];
    *(f32x2*)(out + (size_t)node * DOUT + coff) = o;
}

// ---------------- launcher ----------------

extern "C" void kernel_launch(void* const* d_in, const int* in_sizes, int n_in,
                              void* d_out, int out_size, void* d_ws, size_t ws_size,
                              hipStream_t stream) {
    (void)in_sizes; (void)n_in; (void)out_size; (void)ws_size;
    const float* x_in  = (const float*)d_in[0];
    const int*   ei    = (const int*)d_in[1];
    const float* W_in  = (const float*)d_in[2];
    const float* b_in  = (const float*)d_in[3];
    const float* W_mid = (const float*)d_in[4];
    const float* b_mid = (const float*)d_in[5];
    const float* W_out = (const float*)d_in[6];
    const float* b_out = (const float*)d_in[7];
    const float* gamma = (const float*)d_in[8];
    const float* beta  = (const float*)d_in[9];

    char* ws = (char*)d_ws;
    size_t off = 0;
    auto alloc = [&](size_t bytes) -> char* {
        char* p = ws + off;
        off += (bytes + 255) & ~(size_t)255;
        return p;
    };
    float* dinv   = (float*)alloc((size_t)NN * 4);
    int* counts   = (int*)alloc((size_t)NN * 4);
    int* rowp     = (int*)alloc((size_t)(NN + 1) * 4);
    int* cursor   = (int*)alloc((size_t)NN * 4);
    int* srcs     = (int*)alloc((size_t)NE * 4);
    u16* whi_in   = (u16*)alloc((size_t)DIN * DMID * 2);
    u16* wlo_in   = (u16*)alloc((size_t)DIN * DMID * 2);
    u16* whi_mid  = (u16*)alloc((size_t)NMID * DMID * DMID * 2);
    u16* wlo_mid  = (u16*)alloc((size_t)NMID * DMID * DMID * 2);
    u16* whi_out  = (u16*)alloc((size_t)DMID * DOUT * 2);
    u16* wlo_out  = (u16*)alloc((size_t)DMID * DOUT * 2);
    u16* xhi      = (u16*)alloc((size_t)NN * DMID * 2);  // doubles as aggbuf
    u16* xlo      = (u16*)alloc((size_t)NN * DMID * 2);
    u16* g        = (u16*)alloc((size_t)NN * DMID * 2);

    hipMemsetAsync(counts, 0, (size_t)NN * 4, stream);
    hist_kernel<<<1024, 256, 0, stream>>>(ei, counts);
    dinv_kernel<<<(NN + 255) / 256, 256, 0, stream>>>(counts, dinv);
    scan_kernel<<<1, 1024, 0, stream>>>(counts, rowp, cursor);
    fill_kernel<<<1024, 256, 0, stream>>>(ei, cursor, srcs);

    wsplit_kernel<<<(DIN * DMID + 255) / 256, 256, 0, stream>>>(W_in, whi_in, wlo_in, DIN, DMID);
    for (int i = 0; i < NMID; ++i)
        wsplit_kernel<<<(DMID * DMID + 255) / 256, 256, 0, stream>>>(
            W_mid + (size_t)i * DMID * DMID, whi_mid + (size_t)i * DMID * DMID,
            wlo_mid + (size_t)i * DMID * DMID, DMID, DMID);
    wsplit_kernel<<<(DMID * DOUT + 255) / 256, 256, 0, stream>>>(W_out, whi_out, wlo_out, DMID, DOUT);
    xsplit_kernel<<<1024, 256, 0, stream>>>(x_in, xhi, xlo);

    const int GB = (NN + 63) / 64;   // 782
    const int NB = NN / 4;           // 12500 (4 waves/block, wave per node)
    const dim3 AGRID8(NB, 8);        // node-blocks x chunks
    const dim3 AGRID4(NB, 4);

    // layer 0: 128 -> 256
    gemm_kernel<DIN, DMID><<<GB, 256, 0, stream>>>(xhi, xlo, whi_in, wlo_in, dinv, g);
    agg_chunk_kernel<<<AGRID8, 256, 0, stream>>>(g, rowp, srcs, xhi);
    ln_epilogue_kernel<<<NB, 256, 0, stream>>>(xhi, xlo, dinv, b_in, gamma, beta);
    // 8 mid layers: 256 -> 256
    for (int i = 0; i < NMID; ++i) {
        gemm_kernel<DMID, DMID><<<GB, 256, 0, stream>>>(xhi, xlo,
                                                        whi_mid + (size_t)i * DMID * DMID,
                                                        wlo_mid + (size_t)i * DMID * DMID,
                                                        dinv, g);
        agg_chunk_kernel<<<AGRID8, 256, 0, stream>>>(g, rowp, srcs, xhi);
        ln_epilogue_kernel<<<NB, 256, 0, stream>>>(xhi, xlo, dinv, b_mid + (size_t)i * DMID,
                                                   gamma + (size_t)(i + 1) * DMID,
                                                   beta + (size_t)(i + 1) * DMID);
    }
    // final layer: 256 -> 128, no LN/SiLU
    gemm_kernel<DMID, DOUT><<<GB, 256, 0, stream>>>(xhi, xlo, whi_out, wlo_out, dinv, g);
    agg_chunk_kernel<<<AGRID4, 256, 0, stream>>>(g, rowp, srcs, xhi);
    final_epilogue_kernel<<<NB, 256, 0, stream>>>(xhi, dinv, b_out, (float*)d_out);
}

// Round 7
// 1906.738 us; speedup vs baseline: 1.9772x; 1.5437x over previous
//
#include <hip/hip_runtime.h>
#include <stdint.h>

#define NN   50000
#define NE   1600000
#define DIN  128
#define DMID 256
#define DOUT 128
#define NMID 8

#define AS1 __attribute__((address_space(1)))
#define AS3 __attribute__((address_space(3)))

typedef unsigned short u16;
typedef unsigned int   u32;
typedef __attribute__((ext_vector_type(8))) short short8;
typedef __attribute__((ext_vector_type(4))) float f32x4;
typedef __attribute__((ext_vector_type(2))) float f32x2;

__device__ __forceinline__ float bf2f(u32 u) {
    union { u32 i; float f; } c; c.i = u << 16; return c.f;
}
__device__ __forceinline__ u16 f2bf(float f) {
    union { float f; u32 i; } c; c.f = f;
    u32 u = c.i;
    return (u16)((u + 0x7fffu + ((u >> 16) & 1u)) >> 16);
}
__device__ __forceinline__ void split2(float v, u16& hi, u16& lo) {
    hi = f2bf(v);
    float r = v - bf2f(hi);
    lo = f2bf(r);
}

// ---------------- preprocessing kernels ----------------

__global__ void hist_kernel(const int* __restrict__ ei, int* __restrict__ counts) {
    int i = blockIdx.x * blockDim.x + threadIdx.x;
    int stride = gridDim.x * blockDim.x;
    for (; i < NE; i += stride) atomicAdd(&counts[ei[NE + i]], 1);
}

__global__ void dinv_kernel(const int* __restrict__ counts, float* __restrict__ dinv) {
    int i = blockIdx.x * blockDim.x + threadIdx.x;
    if (i < NN) dinv[i] = rsqrtf((float)counts[i] + 1.0f);
}

__global__ __launch_bounds__(1024) void scan_kernel(const int* __restrict__ counts,
                                                    int* __restrict__ rowp,
                                                    int* __restrict__ cursor) {
    __shared__ int sh[1024];
    const int t = threadIdx.x;
    constexpr int ITEMS = (NN + 1023) / 1024;  // 49
    const int start = t * ITEMS;
    int sum = 0;
    for (int j = 0; j < ITEMS; ++j) {
        int idx = start + j;
        if (idx < NN) sum += counts[idx];
    }
    sh[t] = sum;
    __syncthreads();
    for (int offs = 1; offs < 1024; offs <<= 1) {
        int v = (t >= offs) ? sh[t - offs] : 0;
        __syncthreads();
        sh[t] += v;
        __syncthreads();
    }
    int base = (t == 0) ? 0 : sh[t - 1];
    for (int j = 0; j < ITEMS; ++j) {
        int idx = start + j;
        if (idx < NN) {
            rowp[idx] = base;
            cursor[idx] = base;
            base += counts[idx];
        }
    }
    if (t == 0) rowp[NN] = NE;
}

__global__ void fill_kernel(const int* __restrict__ ei, int* __restrict__ cursor,
                            int* __restrict__ srcs) {
    int i = blockIdx.x * blockDim.x + threadIdx.x;
    int stride = gridDim.x * blockDim.x;
    for (; i < NE; i += stride) {
        int d = ei[NE + i];
        int pos = atomicAdd(&cursor[d], 1);
        srcs[pos] = ei[i];
    }
}

// W [K x Dc] fp32 row-major -> slice-major bf16 split: Whi[((k/32)*Dc + d)*32 + k%32]
__global__ void wsplit_kernel(const float* __restrict__ W, u16* __restrict__ Whi,
                              u16* __restrict__ Wlo, int K, int Dc) {
    int idx = blockIdx.x * blockDim.x + threadIdx.x;
    if (idx < K * Dc) {
        int k = idx / Dc, d = idx - k * Dc;
        u16 hi, lo;
        split2(W[idx], hi, lo);
        size_t o = ((size_t)(k >> 5) * Dc + d) * 32 + (k & 31);
        Whi[o] = hi;
        Wlo[o] = lo;
    }
}

// x [NN][128] fp32 -> row-major bf16 hi/lo
__global__ void xsplit_kernel(const float* __restrict__ x, u16* __restrict__ xhi,
                              u16* __restrict__ xlo) {
    int i = blockIdx.x * blockDim.x + threadIdx.x;
    int stride = gridDim.x * blockDim.x;
    for (; i < NN * DIN; i += stride) {
        u16 hi, lo;
        split2(x[i], hi, lo);
        xhi[i] = hi;
        xlo[i] = lo;
    }
}

// ---------------- GEMM: g = (x @ W) * dinv[row], bf16 row-major out ----------
// x row-major [NN][K] bf16 hi+lo; W slice-major [K/32][Dc][32] bf16 hi+lo.
// Per K-slice: stage B-slice (Dc x 32, hi+lo) into LDS via global_load_lds(16B),
// fragments via ds_read_b128, 3-pass split-bf16 MFMA (xh*Wh + xl*Wh + xh*Wl).
// block = 256 = 4 waves; wave: 16 rows x Dc cols. C/D: col=lane&15, row=quad*4+reg.

template <int K, int Dc>
__global__ __launch_bounds__(256) void gemm_kernel(const u16* __restrict__ xhi,
                                                   const u16* __restrict__ xlo,
                                                   const u16* __restrict__ whi,
                                                   const u16* __restrict__ wlo,
                                                   const float* __restrict__ dinv,
                                                   u16* __restrict__ g) {
    constexpr int NT = Dc / 16;
    constexpr int KS = K / 32;
    __shared__ u16 bh[Dc * 32];
    __shared__ u16 bl[Dc * 32];
    const int tid = threadIdx.x;
    const int wid = tid >> 6;
    const int lane = tid & 63;
    const int m = lane & 15, quad = lane >> 4;
    const int rowBase = blockIdx.x * 64 + wid * 16;
    int rowA = rowBase + m;
    if (rowA > NN - 1) rowA = NN - 1;  // clamp; no early return (barriers!)

    f32x4 acc[NT];
#pragma unroll
    for (int t = 0; t < NT; ++t) acc[t] = (f32x4){0.f, 0.f, 0.f, 0.f};

    const u16* ph = xhi + (size_t)rowA * K + quad * 8;
    const u16* pl = xlo + (size_t)rowA * K + quad * 8;

    for (int ks = 0; ks < KS; ++ks) {
        const u16* sh_src = whi + (size_t)ks * Dc * 32;
        const u16* sl_src = wlo + (size_t)ks * Dc * 32;
        __syncthreads();  // protect LDS from previous iteration's readers
#pragma unroll
        for (int i = 0; i < Dc * 4; i += 256) {
            int j = i + tid;
            __builtin_amdgcn_global_load_lds((const AS1 void*)(sh_src + j * 8),
                                             (AS3 void*)((AS3 u16*)bh + j * 8), 16, 0, 0);
            __builtin_amdgcn_global_load_lds((const AS1 void*)(sl_src + j * 8),
                                             (AS3 void*)((AS3 u16*)bl + j * 8), 16, 0, 0);
        }
        short8 ah = *(const short8*)(ph + ks * 32);
        short8 al = *(const short8*)(pl + ks * 32);
        __syncthreads();  // staging complete
#pragma unroll
        for (int t = 0; t < NT; ++t) {
            const int bo = (t * 16 + m) * 32 + quad * 8;
            short8 wh = *(const short8*)(bh + bo);
            short8 wl = *(const short8*)(bl + bo);
            acc[t] = __builtin_amdgcn_mfma_f32_16x16x32_bf16(ah, wh, acc[t], 0, 0, 0);
            acc[t] = __builtin_amdgcn_mfma_f32_16x16x32_bf16(al, wh, acc[t], 0, 0, 0);
            acc[t] = __builtin_amdgcn_mfma_f32_16x16x32_bf16(ah, wl, acc[t], 0, 0, 0);
        }
    }

    const int r0 = rowBase + quad * 4;
    float dv[4];
#pragma unroll
    for (int r = 0; r < 4; ++r) {
        int rr = r0 + r;
        dv[r] = (rr < NN) ? dinv[rr] : 0.f;
    }
#pragma unroll
    for (int t = 0; t < NT; ++t) {
#pragma unroll
        for (int r = 0; r < 4; ++r) {
            int rr = r0 + r;
            if (rr < NN) g[(size_t)rr * Dc + t * 16 + m] = f2bf(acc[t][r] * dv[r]);
        }
    }
}

// ---------------- full-row aggregation + fused bias/LN/SiLU/split ------------
// wave per node; lane owns L = Dc/64 consecutive bf16 columns (full 512B row per
// edge = 8 contiguous lines -> high gather throughput). 8-deep unrolled.

template <int L>
__device__ __forceinline__ void loadg(const u16* p, float (&f)[L]);
template <>
__device__ __forceinline__ void loadg<4>(const u16* p, float (&f)[4]) {
    uint2 v = *(const uint2*)p;
    f[0] = bf2f(v.x & 0xffffu); f[1] = bf2f(v.x >> 16);
    f[2] = bf2f(v.y & 0xffffu); f[3] = bf2f(v.y >> 16);
}
template <>
__device__ __forceinline__ void loadg<2>(const u16* p, float (&f)[2]) {
    u32 v = *(const u32*)p;
    f[0] = bf2f(v & 0xffffu); f[1] = bf2f(v >> 16);
}

template <int Dc, bool FINAL>
__global__ __launch_bounds__(256) void agg_kernel(const u16* __restrict__ g,
                                                  const int* __restrict__ rowp,
                                                  const int* __restrict__ srcs,
                                                  const float* __restrict__ dinv,
                                                  const float* __restrict__ bias,
                                                  const float* __restrict__ gamma,
                                                  const float* __restrict__ beta,
                                                  float* __restrict__ outf,
                                                  u16* __restrict__ xhi,
                                                  u16* __restrict__ xlo) {
    constexpr int L = Dc / 64;
    const int wid = threadIdx.x >> 6, lane = threadIdx.x & 63;
    const int node = blockIdx.x * 4 + wid;
    const int coff = lane * L;

    float acc[L];
    loadg<L>(g + (size_t)node * Dc + coff, acc);  // self term

    int e = rowp[node];
    const int end = rowp[node + 1];
    for (; e + 8 <= end; e += 8) {
        int s0 = srcs[e],     s1 = srcs[e + 1], s2 = srcs[e + 2], s3 = srcs[e + 3];
        int s4 = srcs[e + 4], s5 = srcs[e + 5], s6 = srcs[e + 6], s7 = srcs[e + 7];
        float f0[L], f1[L], f2[L], f3[L], f4[L], f5[L], f6[L], f7[L];
        loadg<L>(g + (size_t)s0 * Dc + coff, f0);
        loadg<L>(g + (size_t)s1 * Dc + coff, f1);
        loadg<L>(g + (size_t)s2 * Dc + coff, f2);
        loadg<L>(g + (size_t)s3 * Dc + coff, f3);
        loadg<L>(g + (size_t)s4 * Dc + coff, f4);
        loadg<L>(g + (size_t)s5 * Dc + coff, f5);
        loadg<L>(g + (size_t)s6 * Dc + coff, f6);
        loadg<L>(g + (size_t)s7 * Dc + coff, f7);
#pragma unroll
        for (int j = 0; j < L; ++j)
            acc[j] += ((f0[j] + f1[j]) + (f2[j] + f3[j])) +
                      ((f4[j] + f5[j]) + (f6[j] + f7[j]));
    }
    for (; e < end; ++e) {
        float f[L];
        loadg<L>(g + (size_t)srcs[e] * Dc + coff, f);
#pragma unroll
        for (int j = 0; j < L; ++j) acc[j] += f[j];
    }

    const float dv = dinv[node];
    float v[L];
#pragma unroll
    for (int j = 0; j < L; ++j) v[j] = acc[j] * dv + bias[coff + j];

    if (FINAL) {
        if (L == 4) {
            f32x4 o = {v[0], v[1], v[2], v[3]};
            *(f32x4*)(outf + (size_t)node * Dc + coff) = o;
        } else {
            f32x2 o = {v[0], v[1]};
            *(f32x2*)(outf + (size_t)node * Dc + coff) = o;
        }
    } else {
        float s = 0.f, s2 = 0.f;
#pragma unroll
        for (int j = 0; j < L; ++j) {
            s += v[j];
            s2 += v[j] * v[j];
        }
        for (int off = 32; off > 0; off >>= 1) {
            s += __shfl_xor(s, off, 64);
            s2 += __shfl_xor(s2, off, 64);
        }
        const float mu = s * (1.f / Dc);
        const float var = s2 * (1.f / Dc) - mu * mu;
        const float rstd = rsqrtf(fmaxf(var, 0.f) + 1e-5f);
#pragma unroll
        for (int j = 0; j < L; ++j) {
            float y = (v[j] - mu) * rstd * gamma[coff + j] + beta[coff + j];
            v[j] = y / (1.f + __expf(-y));
        }
        u16 hh[L], ll[L];
#pragma unroll
        for (int j = 0; j < L; ++j) split2(v[j], hh[j], ll[j]);
        if (L == 4) {
            uint2 oh, ol;
            oh.x = (u32)hh[0] | ((u32)hh[1] << 16);
            oh.y = (u32)hh[2] | ((u32)hh[3] << 16);
            ol.x = (u32)ll[0] | ((u32)ll[1] << 16);
            ol.y = (u32)ll[2] | ((u32)ll[3] << 16);
            *(uint2*)(xhi + (size_t)node * Dc + coff) = oh;
            *(uint2*)(xlo + (size_t)node * Dc + coff) = ol;
        } else {
            *(u32*)(xhi + (size_t)node * Dc + coff) = (u32)hh[0] | ((u32)hh[1] << 16);
            *(u32*)(xlo + (size_t)node * Dc + coff) = (u32)ll[0] | ((u32)ll[1] << 16);
        }
    }
}

// ---------------- launcher ----------------

extern "C" void kernel_launch(void* const* d_in, const int* in_sizes, int n_in,
                              void* d_out, int out_size, void* d_ws, size_t ws_size,
                              hipStream_t stream) {
    (void)in_sizes; (void)n_in; (void)out_size; (void)ws_size;
    const float* x_in  = (const float*)d_in[0];
    const int*   ei    = (const int*)d_in[1];
    const float* W_in  = (const float*)d_in[2];
    const float* b_in  = (const float*)d_in[3];
    const float* W_mid = (const float*)d_in[4];
    const float* b_mid = (const float*)d_in[5];
    const float* W_out = (const float*)d_in[6];
    const float* b_out = (const float*)d_in[7];
    const float* gamma = (const float*)d_in[8];
    const float* beta  = (const float*)d_in[9];

    char* ws = (char*)d_ws;
    size_t off = 0;
    auto alloc = [&](size_t bytes) -> char* {
        char* p = ws + off;
        off += (bytes + 255) & ~(size_t)255;
        return p;
    };
    float* dinv   = (float*)alloc((size_t)NN * 4);
    int* counts   = (int*)alloc((size_t)NN * 4);
    int* rowp     = (int*)alloc((size_t)(NN + 1) * 4);
    int* cursor   = (int*)alloc((size_t)NN * 4);
    int* srcs     = (int*)alloc((size_t)NE * 4);
    u16* whi_in   = (u16*)alloc((size_t)DIN * DMID * 2);
    u16* wlo_in   = (u16*)alloc((size_t)DIN * DMID * 2);
    u16* whi_mid  = (u16*)alloc((size_t)NMID * DMID * DMID * 2);
    u16* wlo_mid  = (u16*)alloc((size_t)NMID * DMID * DMID * 2);
    u16* whi_out  = (u16*)alloc((size_t)DMID * DOUT * 2);
    u16* wlo_out  = (u16*)alloc((size_t)DMID * DOUT * 2);
    u16* xhi      = (u16*)alloc((size_t)NN * DMID * 2);
    u16* xlo      = (u16*)alloc((size_t)NN * DMID * 2);
    u16* g        = (u16*)alloc((size_t)NN * DMID * 2);

    hipMemsetAsync(counts, 0, (size_t)NN * 4, stream);
    hist_kernel<<<1024, 256, 0, stream>>>(ei, counts);
    dinv_kernel<<<(NN + 255) / 256, 256, 0, stream>>>(counts, dinv);
    scan_kernel<<<1, 1024, 0, stream>>>(counts, rowp, cursor);
    fill_kernel<<<1024, 256, 0, stream>>>(ei, cursor, srcs);

    wsplit_kernel<<<(DIN * DMID + 255) / 256, 256, 0, stream>>>(W_in, whi_in, wlo_in, DIN, DMID);
    for (int i = 0; i < NMID; ++i)
        wsplit_kernel<<<(DMID * DMID + 255) / 256, 256, 0, stream>>>(
            W_mid + (size_t)i * DMID * DMID, whi_mid + (size_t)i * DMID * DMID,
            wlo_mid + (size_t)i * DMID * DMID, DMID, DMID);
    wsplit_kernel<<<(DMID * DOUT + 255) / 256, 256, 0, stream>>>(W_out, whi_out, wlo_out, DMID, DOUT);
    xsplit_kernel<<<1024, 256, 0, stream>>>(x_in, xhi, xlo);

    const int GB = (NN + 63) / 64;   // 782
    const int NB = NN / 4;           // 12500 (4 waves/block, wave per node)

    // layer 0: 128 -> 256
    gemm_kernel<DIN, DMID><<<GB, 256, 0, stream>>>(xhi, xlo, whi_in, wlo_in, dinv, g);
    agg_kernel<DMID, false><<<NB, 256, 0, stream>>>(g, rowp, srcs, dinv, b_in,
                                                    gamma, beta, nullptr, xhi, xlo);
    // 8 mid layers: 256 -> 256
    for (int i = 0; i < NMID; ++i) {
        gemm_kernel<DMID, DMID><<<GB, 256, 0, stream>>>(xhi, xlo,
                                                        whi_mid + (size_t)i * DMID * DMID,
                                                        wlo_mid + (size_t)i * DMID * DMID,
                                                        dinv, g);
        agg_kernel<DMID, false><<<NB, 256, 0, stream>>>(g, rowp, srcs, dinv,
                                                        b_mid + (size_t)i * DMID,
                                                        gamma + (size_t)(i + 1) * DMID,
                                                        beta + (size_t)(i + 1) * DMID,
                                                        nullptr, xhi, xlo);
    }
    // final layer: 256 -> 128, no LN/SiLU
    gemm_kernel<DMID, DOUT><<<GB, 256, 0, stream>>>(xhi, xlo, whi_out, wlo_out, dinv, g);
    agg_kernel<DOUT, true><<<NB, 256, 0, stream>>>(g, rowp, srcs, dinv, b_out,
                                                   nullptr, nullptr, (float*)d_out,
                                                   nullptr, nullptr);
}

// Round 8
// 1782.492 us; speedup vs baseline: 2.1150x; 1.0697x over previous
//
#include <hip/hip_runtime.h>
#include <stdint.h>

#define NN   50000
#define NE   1600000
#define DIN  128
#define DMID 256
#define DOUT 128
#define NMID 8

#define AS1 __attribute__((address_space(1)))
#define AS3 __attribute__((address_space(3)))

typedef unsigned short u16;
typedef unsigned int   u32;
typedef __attribute__((ext_vector_type(8))) short short8;
typedef __attribute__((ext_vector_type(4))) float f32x4;
typedef __attribute__((ext_vector_type(2))) float f32x2;
typedef __attribute__((ext_vector_type(4))) int i32x4;

__device__ __forceinline__ float bf2f(u32 u) {
    union { u32 i; float f; } c; c.i = u << 16; return c.f;
}
__device__ __forceinline__ u16 f2bf(float f) {
    union { float f; u32 i; } c; c.f = f;
    u32 u = c.i;
    return (u16)((u + 0x7fffu + ((u >> 16) & 1u)) >> 16);
}
__device__ __forceinline__ void split2(float v, u16& hi, u16& lo) {
    hi = f2bf(v);
    float r = v - bf2f(hi);
    lo = f2bf(r);
}

// ---------------- preprocessing kernels ----------------

__global__ void hist_kernel(const int* __restrict__ ei, int* __restrict__ counts) {
    int i = (blockIdx.x * blockDim.x + threadIdx.x) * 4;
    if (i < NE) {
        i32x4 d = *(const i32x4*)(ei + NE + i);
        atomicAdd(&counts[d.x], 1);
        atomicAdd(&counts[d.y], 1);
        atomicAdd(&counts[d.z], 1);
        atomicAdd(&counts[d.w], 1);
    }
}

__global__ void dinv_kernel(const int* __restrict__ counts, float* __restrict__ dinv) {
    int i = blockIdx.x * blockDim.x + threadIdx.x;
    if (i < NN) dinv[i] = rsqrtf((float)counts[i] + 1.0f);
}

__global__ __launch_bounds__(1024) void scan_kernel(const int* __restrict__ counts,
                                                    int* __restrict__ rowp,
                                                    int* __restrict__ cursor) {
    __shared__ int sh[1024];
    const int t = threadIdx.x;
    constexpr int ITEMS = (NN + 1023) / 1024;  // 49
    const int start = t * ITEMS;
    int sum = 0;
    for (int j = 0; j < ITEMS; ++j) {
        int idx = start + j;
        if (idx < NN) sum += counts[idx];
    }
    sh[t] = sum;
    __syncthreads();
    for (int offs = 1; offs < 1024; offs <<= 1) {
        int v = (t >= offs) ? sh[t - offs] : 0;
        __syncthreads();
        sh[t] += v;
        __syncthreads();
    }
    int base = (t == 0) ? 0 : sh[t - 1];
    for (int j = 0; j < ITEMS; ++j) {
        int idx = start + j;
        if (idx < NN) {
            rowp[idx] = base;
            cursor[idx] = base;
            base += counts[idx];
        }
    }
    if (t == 0) rowp[NN] = NE;
}

__global__ void fill_kernel(const int* __restrict__ ei, int* __restrict__ cursor,
                            int* __restrict__ srcs) {
    int i = (blockIdx.x * blockDim.x + threadIdx.x) * 4;
    if (i < NE) {
        i32x4 d = *(const i32x4*)(ei + NE + i);
        i32x4 s = *(const i32x4*)(ei + i);
        int p0 = atomicAdd(&cursor[d.x], 1);
        int p1 = atomicAdd(&cursor[d.y], 1);
        int p2 = atomicAdd(&cursor[d.z], 1);
        int p3 = atomicAdd(&cursor[d.w], 1);
        srcs[p0] = s.x;
        srcs[p1] = s.y;
        srcs[p2] = s.z;
        srcs[p3] = s.w;
    }
}

// W [K x Dc] fp32 row-major -> slice-major bf16 split: Whi[((k/32)*Dc + d)*32 + k%32]
__global__ void wsplit_kernel(const float* __restrict__ W, u16* __restrict__ Whi,
                              u16* __restrict__ Wlo, int K, int Dc) {
    int idx = blockIdx.x * blockDim.x + threadIdx.x;
    if (idx < K * Dc) {
        int k = idx / Dc, d = idx - k * Dc;
        u16 hi, lo;
        split2(W[idx], hi, lo);
        size_t o = ((size_t)(k >> 5) * Dc + d) * 32 + (k & 31);
        Whi[o] = hi;
        Wlo[o] = lo;
    }
}

// x [NN][128] fp32 -> row-major bf16 hi/lo
__global__ void xsplit_kernel(const float* __restrict__ x, u16* __restrict__ xhi,
                              u16* __restrict__ xlo) {
    int i = blockIdx.x * blockDim.x + threadIdx.x;
    int stride = gridDim.x * blockDim.x;
    for (; i < NN * DIN; i += stride) {
        u16 hi, lo;
        split2(x[i], hi, lo);
        xhi[i] = hi;
        xlo[i] = lo;
    }
}

// ---------------- GEMM: g = (x @ W) * dinv[row], bf16 row-major out ----------
// x row-major [NN][K] bf16 hi+lo; W slice-major [K/32][Dc][32] bf16 hi+lo.
// 512 threads = 8 waves; block covers 128 rows (16/wave), staging amortized 2x
// vs 64-row blocks. Per K-slice: stage B-slice (Dc x 32, hi+lo) into LDS via
// global_load_lds(16B); fragments via ds_read_b128; 3-pass split-bf16 MFMA.
// C/D: col=lane&15, row=quad*4+reg.

template <int K, int Dc>
__global__ __launch_bounds__(512) void gemm_kernel(const u16* __restrict__ xhi,
                                                   const u16* __restrict__ xlo,
                                                   const u16* __restrict__ whi,
                                                   const u16* __restrict__ wlo,
                                                   const float* __restrict__ dinv,
                                                   u16* __restrict__ g) {
    constexpr int NT = Dc / 16;
    constexpr int KS = K / 32;
    __shared__ u16 bh[Dc * 32];
    __shared__ u16 bl[Dc * 32];
    const int tid = threadIdx.x;
    const int wid = tid >> 6;
    const int lane = tid & 63;
    const int m = lane & 15, quad = lane >> 4;
    const int rowBase = blockIdx.x * 128 + wid * 16;
    int rowA = rowBase + m;
    if (rowA > NN - 1) rowA = NN - 1;  // clamp; no early return (barriers!)

    f32x4 acc[NT];
#pragma unroll
    for (int t = 0; t < NT; ++t) acc[t] = (f32x4){0.f, 0.f, 0.f, 0.f};

    const u16* ph = xhi + (size_t)rowA * K + quad * 8;
    const u16* pl = xlo + (size_t)rowA * K + quad * 8;

    for (int ks = 0; ks < KS; ++ks) {
        const u16* sh_src = whi + (size_t)ks * Dc * 32;
        const u16* sl_src = wlo + (size_t)ks * Dc * 32;
        __syncthreads();  // protect LDS from previous iteration's readers
#pragma unroll
        for (int i = 0; i < Dc * 4; i += 512) {
            int j = i + tid;
            __builtin_amdgcn_global_load_lds((const AS1 void*)(sh_src + j * 8),
                                             (AS3 void*)((AS3 u16*)bh + j * 8), 16, 0, 0);
            __builtin_amdgcn_global_load_lds((const AS1 void*)(sl_src + j * 8),
                                             (AS3 void*)((AS3 u16*)bl + j * 8), 16, 0, 0);
        }
        short8 ah = *(const short8*)(ph + ks * 32);
        short8 al = *(const short8*)(pl + ks * 32);
        __syncthreads();  // staging complete
#pragma unroll
        for (int t = 0; t < NT; ++t) {
            const int bo = (t * 16 + m) * 32 + quad * 8;
            short8 wh = *(const short8*)(bh + bo);
            short8 wl = *(const short8*)(bl + bo);
            acc[t] = __builtin_amdgcn_mfma_f32_16x16x32_bf16(ah, wh, acc[t], 0, 0, 0);
            acc[t] = __builtin_amdgcn_mfma_f32_16x16x32_bf16(al, wh, acc[t], 0, 0, 0);
            acc[t] = __builtin_amdgcn_mfma_f32_16x16x32_bf16(ah, wl, acc[t], 0, 0, 0);
        }
    }

    const int r0 = rowBase + quad * 4;
    float dv[4];
#pragma unroll
    for (int r = 0; r < 4; ++r) {
        int rr = r0 + r;
        dv[r] = (rr < NN) ? dinv[rr] : 0.f;
    }
#pragma unroll
    for (int t = 0; t < NT; ++t) {
#pragma unroll
        for (int r = 0; r < 4; ++r) {
            int rr = r0 + r;
            if (rr < NN) g[(size_t)rr * Dc + t * 16 + m] = f2bf(acc[t][r] * dv[r]);
        }
    }
}

// ---------------- full-row aggregation + fused bias/LN/SiLU/split ------------
// wave per node; lane owns L = Dc/64 consecutive bf16 columns (full 512B row per
// edge = 8 contiguous lines -> high gather throughput). 8-deep unrolled.

template <int L>
__device__ __forceinline__ void loadg(const u16* p, float (&f)[L]);
template <>
__device__ __forceinline__ void loadg<4>(const u16* p, float (&f)[4]) {
    uint2 v = *(const uint2*)p;
    f[0] = bf2f(v.x & 0xffffu); f[1] = bf2f(v.x >> 16);
    f[2] = bf2f(v.y & 0xffffu); f[3] = bf2f(v.y >> 16);
}
template <>
__device__ __forceinline__ void loadg<2>(const u16* p, float (&f)[2]) {
    u32 v = *(const u32*)p;
    f[0] = bf2f(v & 0xffffu); f[1] = bf2f(v >> 16);
}

template <int Dc, bool FINAL>
__global__ __launch_bounds__(256) void agg_kernel(const u16* __restrict__ g,
                                                  const int* __restrict__ rowp,
                                                  const int* __restrict__ srcs,
                                                  const float* __restrict__ dinv,
                                                  const float* __restrict__ bias,
                                                  const float* __restrict__ gamma,
                                                  const float* __restrict__ beta,
                                                  float* __restrict__ outf,
                                                  u16* __restrict__ xhi,
                                                  u16* __restrict__ xlo) {
    constexpr int L = Dc / 64;
    const int wid = threadIdx.x >> 6, lane = threadIdx.x & 63;
    const int node = blockIdx.x * 4 + wid;
    const int coff = lane * L;

    float acc[L];
    loadg<L>(g + (size_t)node * Dc + coff, acc);  // self term

    int e = rowp[node];
    const int end = rowp[node + 1];
    for (; e + 8 <= end; e += 8) {
        int s0 = srcs[e],     s1 = srcs[e + 1], s2 = srcs[e + 2], s3 = srcs[e + 3];
        int s4 = srcs[e + 4], s5 = srcs[e + 5], s6 = srcs[e + 6], s7 = srcs[e + 7];
        float f0[L], f1[L], f2[L], f3[L], f4[L], f5[L], f6[L], f7[L];
        loadg<L>(g + (size_t)s0 * Dc + coff, f0);
        loadg<L>(g + (size_t)s1 * Dc + coff, f1);
        loadg<L>(g + (size_t)s2 * Dc + coff, f2);
        loadg<L>(g + (size_t)s3 * Dc + coff, f3);
        loadg<L>(g + (size_t)s4 * Dc + coff, f4);
        loadg<L>(g + (size_t)s5 * Dc + coff, f5);
        loadg<L>(g + (size_t)s6 * Dc + coff, f6);
        loadg<L>(g + (size_t)s7 * Dc + coff, f7);
#pragma unroll
        for (int j = 0; j < L; ++j)
            acc[j] += ((f0[j] + f1[j]) + (f2[j] + f3[j])) +
                      ((f4[j] + f5[j]) + (f6[j] + f7[j]));
    }
    for (; e < end; ++e) {
        float f[L];
        loadg<L>(g + (size_t)srcs[e] * Dc + coff, f);
#pragma unroll
        for (int j = 0; j < L; ++j) acc[j] += f[j];
    }

    const float dv = dinv[node];
    float v[L];
#pragma unroll
    for (int j = 0; j < L; ++j) v[j] = acc[j] * dv + bias[coff + j];

    if (FINAL) {
        if (L == 4) {
            f32x4 o = {v[0], v[1], v[2], v[3]};
            *(f32x4*)(outf + (size_t)node * Dc + coff) = o;
        } else {
            f32x2 o = {v[0], v[1]};
            *(f32x2*)(outf + (size_t)node * Dc + coff) = o;
        }
    } else {
        float s = 0.f, s2 = 0.f;
#pragma unroll
        for (int j = 0; j < L; ++j) {
            s += v[j];
            s2 += v[j] * v[j];
        }
        for (int off = 32; off > 0; off >>= 1) {
            s += __shfl_xor(s, off, 64);
            s2 += __shfl_xor(s2, off, 64);
        }
        const float mu = s * (1.f / Dc);
        const float var = s2 * (1.f / Dc) - mu * mu;
        const float rstd = rsqrtf(fmaxf(var, 0.f) + 1e-5f);
#pragma unroll
        for (int j = 0; j < L; ++j) {
            float y = (v[j] - mu) * rstd * gamma[coff + j] + beta[coff + j];
            v[j] = y / (1.f + __expf(-y));
        }
        u16 hh[L], ll[L];
#pragma unroll
        for (int j = 0; j < L; ++j) split2(v[j], hh[j], ll[j]);
        if (L == 4) {
            uint2 oh, ol;
            oh.x = (u32)hh[0] | ((u32)hh[1] << 16);
            oh.y = (u32)hh[2] | ((u32)hh[3] << 16);
            ol.x = (u32)ll[0] | ((u32)ll[1] << 16);
            ol.y = (u32)ll[2] | ((u32)ll[3] << 16);
            *(uint2*)(xhi + (size_t)node * Dc + coff) = oh;
            *(uint2*)(xlo + (size_t)node * Dc + coff) = ol;
        } else {
            *(u32*)(xhi + (size_t)node * Dc + coff) = (u32)hh[0] | ((u32)hh[1] << 16);
            *(u32*)(xlo + (size_t)node * Dc + coff) = (u32)ll[0] | ((u32)ll[1] << 16);
        }
    }
}

// ---------------- launcher ----------------

extern "C" void kernel_launch(void* const* d_in, const int* in_sizes, int n_in,
                              void* d_out, int out_size, void* d_ws, size_t ws_size,
                              hipStream_t stream) {
    (void)in_sizes; (void)n_in; (void)out_size; (void)ws_size;
    const float* x_in  = (const float*)d_in[0];
    const int*   ei    = (const int*)d_in[1];
    const float* W_in  = (const float*)d_in[2];
    const float* b_in  = (const float*)d_in[3];
    const float* W_mid = (const float*)d_in[4];
    const float* b_mid = (const float*)d_in[5];
    const float* W_out = (const float*)d_in[6];
    const float* b_out = (const float*)d_in[7];
    const float* gamma = (const float*)d_in[8];
    const float* beta  = (const float*)d_in[9];

    char* ws = (char*)d_ws;
    size_t off = 0;
    auto alloc = [&](size_t bytes) -> char* {
        char* p = ws + off;
        off += (bytes + 255) & ~(size_t)255;
        return p;
    };
    float* dinv   = (float*)alloc((size_t)NN * 4);
    int* counts   = (int*)alloc((size_t)NN * 4);
    int* rowp     = (int*)alloc((size_t)(NN + 1) * 4);
    int* cursor   = (int*)alloc((size_t)NN * 4);
    int* srcs     = (int*)alloc((size_t)NE * 4);
    u16* whi_in   = (u16*)alloc((size_t)DIN * DMID * 2);
    u16* wlo_in   = (u16*)alloc((size_t)DIN * DMID * 2);
    u16* whi_mid  = (u16*)alloc((size_t)NMID * DMID * DMID * 2);
    u16* wlo_mid  = (u16*)alloc((size_t)NMID * DMID * DMID * 2);
    u16* whi_out  = (u16*)alloc((size_t)DMID * DOUT * 2);
    u16* wlo_out  = (u16*)alloc((size_t)DMID * DOUT * 2);
    u16* xhi      = (u16*)alloc((size_t)NN * DMID * 2);
    u16* xlo      = (u16*)alloc((size_t)NN * DMID * 2);
    u16* g        = (u16*)alloc((size_t)NN * DMID * 2);

    hipMemsetAsync(counts, 0, (size_t)NN * 4, stream);
    const int EB4 = (NE / 4 + 255) / 256;  // 1563: one int4 group per thread
    hist_kernel<<<EB4, 256, 0, stream>>>(ei, counts);
    dinv_kernel<<<(NN + 255) / 256, 256, 0, stream>>>(counts, dinv);
    scan_kernel<<<1, 1024, 0, stream>>>(counts, rowp, cursor);
    fill_kernel<<<EB4, 256, 0, stream>>>(ei, cursor, srcs);

    wsplit_kernel<<<(DIN * DMID + 255) / 256, 256, 0, stream>>>(W_in, whi_in, wlo_in, DIN, DMID);
    for (int i = 0; i < NMID; ++i)
        wsplit_kernel<<<(DMID * DMID + 255) / 256, 256, 0, stream>>>(
            W_mid + (size_t)i * DMID * DMID, whi_mid + (size_t)i * DMID * DMID,
            wlo_mid + (size_t)i * DMID * DMID, DMID, DMID);
    wsplit_kernel<<<(DMID * DOUT + 255) / 256, 256, 0, stream>>>(W_out, whi_out, wlo_out, DMID, DOUT);
    xsplit_kernel<<<1024, 256, 0, stream>>>(x_in, xhi, xlo);

    const int GB = (NN + 127) / 128;  // 391 (8 waves/block, 128 rows/block)
    const int NB = NN / 4;            // 12500 (4 waves/block, wave per node)

    // layer 0: 128 -> 256
    gemm_kernel<DIN, DMID><<<GB, 512, 0, stream>>>(xhi, xlo, whi_in, wlo_in, dinv, g);
    agg_kernel<DMID, false><<<NB, 256, 0, stream>>>(g, rowp, srcs, dinv, b_in,
                                                    gamma, beta, nullptr, xhi, xlo);
    // 8 mid layers: 256 -> 256
    for (int i = 0; i < NMID; ++i) {
        gemm_kernel<DMID, DMID><<<GB, 512, 0, stream>>>(xhi, xlo,
                                                        whi_mid + (size_t)i * DMID * DMID,
                                                        wlo_mid + (size_t)i * DMID * DMID,
                                                        dinv, g);
        agg_kernel<DMID, false><<<NB, 256, 0, stream>>>(g, rowp, srcs, dinv,
                                                        b_mid + (size_t)i * DMID,
                                                        gamma + (size_t)(i + 1) * DMID,
                                                        beta + (size_t)(i + 1) * DMID,
                                                        nullptr, xhi, xlo);
    }
    // final layer: 256 -> 128, no LN/SiLU
    gemm_kernel<DMID, DOUT><<<GB, 512, 0, stream>>>(xhi, xlo, whi_out, wlo_out, dinv, g);
    agg_kernel<DOUT, true><<<NB, 256, 0, stream>>>(g, rowp, srcs, dinv, b_out,
                                                   nullptr, nullptr, (float*)d_out,
                                                   nullptr, nullptr);
}